// Round 11
// baseline (40.892 us; speedup 1.0000x reference)
//
#include <hip/hip_runtime.h>
#include <math.h>

#define N  2048
#define K  8
#define NK 1024
#define R  2             // rows per block
#define W  1024          // column window per block
#define TPB 256
#define TAU_C 0.5f
#define TAU_S 0.5f

// Single fused kernel (replay-safe per R8): block rebuilds index maps from the
// immutable input `idx` into LDS, then serves R rows x W columns.
// Occupancy-first config: 2048 blocks (8/CU), 16.5 KB LDS, VGPR<=64
// -> targets 32 waves/CU (R9/R10 were grid-capped at 50%).
__global__ void __launch_bounds__(TPB, 8)
fia_fused(const float* __restrict__ adj,
          const int*   __restrict__ idx,
          float* __restrict__ out) {
    __shared__ short jj[K][W];       // 16 KB: position of y in idx[k], or -1
    __shared__ short ixs[K][R];      // position of row x in idx[k], or -1

    const int tid = threadIdx.x;
    const int Y0  = blockIdx.x * W;
    const int X0  = blockIdx.y * R;

    // ---- init maps to -1 (every cell has a unique scan-writer)
    {
        int4  m1 = make_int4(-1, -1, -1, -1);
        int4* p4 = (int4*)&jj[0][0];                 // K*W*2/16 = 1024 int4
        #pragma unroll
        for (int q = 0; q < (K * W * 2) / (16 * TPB); ++q)   // 4
            p4[q * TPB + tid] = m1;
        if (tid < K * R) ((short*)ixs)[tid] = (short)-1;
    }
    __syncthreads();

    // ---- scan idx (8192 entries, coalesced, L1/L2-hot). Unique writer/cell.
    #pragma unroll
    for (int it = 0; it < (K * NK) / TPB; ++it) {    // 32
        int t   = it * TPB + tid;
        int val = idx[t];                            // coalesced
        int k   = t >> 10;                           // uniform per iteration
        int p   = t & (NK - 1);
        int rel = val - Y0;
        if ((unsigned)rel < (unsigned)W) jj[k][rel] = (short)p;
        int relx = val - X0;
        if ((unsigned)relx < (unsigned)R) ixs[k][relx] = (short)p;
    }
    __syncthreads();

    // ---- per-thread column state, hoisted (reused by both rows)
    const int y0 = tid * 4;                          // window-local 4 columns
    int jc[K][4];                                    // clamped j
    int jmask[4] = {0, 0, 0, 0};
    #pragma unroll
    for (int k = 0; k < K; ++k) {
        short4 v = *(const short4*)&jj[k][y0];       // ds_read_b64
        int j0 = v.x, j1 = v.y, j2 = v.z, j3 = v.w;
        jmask[0] |= (j0 >= 0) ? (1 << k) : 0;
        jmask[1] |= (j1 >= 0) ? (1 << k) : 0;
        jmask[2] |= (j2 >= 0) ? (1 << k) : 0;
        jmask[3] |= (j3 >= 0) ? (1 << k) : 0;
        jc[k][0] = j0 & ~(j0 >> 31);                 // max(j,0)
        jc[k][1] = j1 & ~(j1 >> 31);
        jc[k][2] = j2 & ~(j2 >> 31);
        jc[k][3] = j3 & ~(j3 >> 31);
    }

    // ---- row loop (R=2): R9's proven simple schedule — no pipeline games.
    #pragma unroll 1
    for (int r = 0; r < R; ++r) {
        int kp = 0;
        int ixr[K];
        #pragma unroll
        for (int k = 0; k < K; ++k) {
            int v = (int)ixs[k][r];                  // uniform LDS read
            ixr[k] = __builtin_amdgcn_readfirstlane(v);
            kp |= (ixr[k] >= 0) ? (1 << k) : 0;
        }

        float vraw[4][K];
        #pragma unroll
        for (int yy = 0; yy < 4; ++yy)
            #pragma unroll
            for (int k = 0; k < K; ++k) vraw[yy][k] = 0.f;

        #pragma unroll
        for (int k = 0; k < K; ++k) {
            if (ixr[k] >= 0) {                       // SGPR branch
                const float* __restrict__ bk =
                    adj + ((size_t)k * NK + (size_t)ixr[k]) * NK;
                #pragma unroll
                for (int yy = 0; yy < 4; ++yy)
                    vraw[yy][k] = bk[jc[k][yy]];     // consecutive-j gather
            }
        }

        // stats: byte-for-byte the reference's f32 rounding sequence
        // (proven absmax 0.0 across R1/R3-R6/R8-R10). No fast path.
        float res[4];
        #pragma unroll
        for (int yy = 0; yy < 4; ++yy) {
            const int m = jmask[yy] & kp;
            float sum = 0.f;
            #pragma unroll
            for (int k = 0; k < K; ++k) {
                bool p = (m >> k) & 1;
                sum += p ? vraw[yy][k] : 0.f;        // ordered, masked
            }
            float cnt  = (float)__popc(m);
            float n    = fmaxf(cnt, 1e-5f);
            float mean = sum / n;                    // IEEE divide

            float cs = 0.f, vs = 0.f;
            #pragma unroll
            for (int k = 0; k < K; ++k) {
                bool  p = (m >> k) & 1;
                float a = p ? vraw[yy][k] : 0.f;
                cs += (p && (a > TAU_C)) ? 1.f : 0.f;
                float d = a - mean;
                vs += p ? d * d : 0.f;               // select blocks fma-fuse
            }
            float C = cs / n;                        // IEEE divide
            float V = vs / n;                        // IEEE divide
            float S = C * expf(-V);                  // precise expf
            float rr = (S > TAU_S) ? mean : 0.f;
            res[yy] = (cnt > 0.f) ? rr : 0.f;
        }

        float4 o;
        o.x = res[0]; o.y = res[1]; o.z = res[2]; o.w = res[3];
        *(float4*)(out + (size_t)(X0 + r) * N + Y0 + y0) = o;
    }
}

extern "C" void kernel_launch(void* const* d_in, const int* in_sizes, int n_in,
                              void* d_out, int out_size, void* d_ws, size_t ws_size,
                              hipStream_t stream) {
    const float* adj = (const float*)d_in[0];        // (K, NK, NK) f32
    const int*   idx = (const int*)d_in[1];          // (K, NK) i32
    float*       out = (float*)d_out;                // (N, N) f32

    dim3 block(TPB, 1, 1);
    dim3 grid(N / W, N / R, 1);                      // (2, 1024) = 2048 blocks
    fia_fused<<<grid, block, 0, stream>>>(adj, idx, out);
}

// Round 12
// 30.109 us; speedup vs baseline: 1.3581x; 1.3581x over previous
//
#include <hip/hip_runtime.h>
#include <math.h>

#define N  2048
#define K  8
#define NK 1024
#define R  4             // rows per block (maps + staging reused across columns)
#define TPB 512
#define TAU_C 0.5f
#define TAU_S 0.5f

// Single fused kernel (replay-safe class per R8-R11): block rebuilds index maps
// from the immutable `idx` into LDS, then serves R=4 full output rows. Per row,
// the <=8 present clients' 4KB adj rows are STAGED into LDS with coalesced
// float2 loads; the scattered per-output gathers then hit the DS pipe instead
// of the per-CU TA/L1 pipe (R11 falsified occupancy; TA serialization is the
// remaining suspect for the non-VALU ~15us).
__global__ void __launch_bounds__(TPB, 4)
fia_fused(const float* __restrict__ adj,
          const int*   __restrict__ idx,
          float* __restrict__ out) {
    __shared__ short jj[K][N];       // 32 KB: position of y in idx[k], or -1
    __shared__ short ixs[K][R];      // position of row x in idx[k], or -1
    __shared__ float stage[K][NK];   // 32 KB: current row's adj rows

    const int tid = threadIdx.x;
    const int X0  = blockIdx.x * R;

    // ---- init maps to -1 (every jj cell has a unique scan-writer)
    {
        int4  m1 = make_int4(-1, -1, -1, -1);
        int4* p4 = (int4*)&jj[0][0];                 // K*N*2/16 = 2048 int4
        #pragma unroll
        for (int q = 0; q < (K * N * 2) / (16 * TPB); ++q)   // 4
            p4[q * TPB + tid] = m1;
        if (tid < K * R) ((short*)ixs)[tid] = (short)-1;
    }
    __syncthreads();

    // ---- scan idx (8192 entries, coalesced, L2-hot). Unique writer per cell.
    #pragma unroll
    for (int it = 0; it < (K * NK) / TPB; ++it) {    // 16
        int t   = it * TPB + tid;
        int val = idx[t];                            // coalesced
        int k   = t >> 10;                           // uniform per iteration
        int p   = t & (NK - 1);
        jj[k][val] = (short)p;
        int rel = val - X0;
        if ((unsigned)rel < (unsigned)R) ixs[k][rel] = (short)p;
    }
    __syncthreads();

    // ---- per-thread column state, hoisted (reused by all R rows)
    const int y0 = tid * 4;                          // 4 consecutive columns
    int jc[K][4];                                    // clamped j
    int jmask[4] = {0, 0, 0, 0};
    #pragma unroll
    for (int k = 0; k < K; ++k) {
        short4 v = *(const short4*)&jj[k][y0];       // ds_read_b64
        int j0 = v.x, j1 = v.y, j2 = v.z, j3 = v.w;
        jmask[0] |= (j0 >= 0) ? (1 << k) : 0;
        jmask[1] |= (j1 >= 0) ? (1 << k) : 0;
        jmask[2] |= (j2 >= 0) ? (1 << k) : 0;
        jmask[3] |= (j3 >= 0) ? (1 << k) : 0;
        jc[k][0] = j0 & ~(j0 >> 31);                 // max(j,0)
        jc[k][1] = j1 & ~(j1 >> 31);
        jc[k][2] = j2 & ~(j2 >> 31);
        jc[k][3] = j3 & ~(j3 >> 31);
    }

    // ---- row loop
    #pragma unroll 1
    for (int r = 0; r < R; ++r) {
        int kp = 0;
        int ixr[K];
        #pragma unroll
        for (int k = 0; k < K; ++k) {
            int v = (int)ixs[k][r];                  // uniform LDS read
            ixr[k] = __builtin_amdgcn_readfirstlane(v);
            kp |= (ixr[k] >= 0) ? (1 << k) : 0;
        }

        if (r > 0) __syncthreads();                  // WAR: prev row done reading stage

        // STAGE: coalesced float2 per present client row. Issue phase uses
        // statically-indexed sr[k] (full unroll) so loads can batch-issue.
        float2 sr[K];
        #pragma unroll
        for (int k = 0; k < K; ++k) {
            if (ixr[k] >= 0) {                       // scalar branch
                const float2* __restrict__ src =
                    (const float2*)(adj + ((size_t)k * NK + (size_t)ixr[k]) * NK);
                sr[k] = src[tid];                    // fully coalesced 8B
            }
        }
        #pragma unroll
        for (int k = 0; k < K; ++k) {
            if (ixr[k] >= 0)
                ((float2*)&stage[k][0])[tid] = sr[k];   // ds_write_b64, conflict-free
        }
        __syncthreads();                             // stage visible (vmcnt+barrier)

        // GATHER from LDS (DS pipe; ~2-4-way conflicts, cheap per m136)
        float vraw[4][K];
        #pragma unroll
        for (int yy = 0; yy < 4; ++yy)
            #pragma unroll
            for (int k = 0; k < K; ++k) vraw[yy][k] = 0.f;

        #pragma unroll
        for (int k = 0; k < K; ++k) {
            if (ixr[k] >= 0) {                       // scalar branch
                #pragma unroll
                for (int yy = 0; yy < 4; ++yy)
                    vraw[yy][k] = stage[k][jc[k][yy]];   // ds_read_b32
            }
        }

        // STATS: byte-for-byte the reference's f32 rounding sequence
        // (proven absmax 0.0 across R1/R3-R6/R8-R11). No fast path.
        float res[4];
        #pragma unroll
        for (int yy = 0; yy < 4; ++yy) {
            const int m = jmask[yy] & kp;
            float sum = 0.f;
            #pragma unroll
            for (int k = 0; k < K; ++k) {
                bool p = (m >> k) & 1;
                sum += p ? vraw[yy][k] : 0.f;        // ordered, masked
            }
            float cnt  = (float)__popc(m);
            float n    = fmaxf(cnt, 1e-5f);
            float mean = sum / n;                    // IEEE divide

            float cs = 0.f, vs = 0.f;
            #pragma unroll
            for (int k = 0; k < K; ++k) {
                bool  p = (m >> k) & 1;
                float a = p ? vraw[yy][k] : 0.f;
                cs += (p && (a > TAU_C)) ? 1.f : 0.f;
                float d = a - mean;
                vs += p ? d * d : 0.f;               // select blocks fma-fuse
            }
            float C = cs / n;                        // IEEE divide
            float V = vs / n;                        // IEEE divide
            float S = C * expf(-V);                  // precise expf
            float rr = (S > TAU_S) ? mean : 0.f;
            res[yy] = (cnt > 0.f) ? rr : 0.f;
        }

        float4 o;
        o.x = res[0]; o.y = res[1]; o.z = res[2]; o.w = res[3];
        *(float4*)(out + (size_t)(X0 + r) * N + y0) = o;
    }
}

extern "C" void kernel_launch(void* const* d_in, const int* in_sizes, int n_in,
                              void* d_out, int out_size, void* d_ws, size_t ws_size,
                              hipStream_t stream) {
    const float* adj = (const float*)d_in[0];        // (K, NK, NK) f32
    const int*   idx = (const int*)d_in[1];          // (K, NK) i32
    float*       out = (float*)d_out;                // (N, N) f32

    dim3 block(TPB, 1, 1);
    dim3 grid(N / R, 1, 1);                          // 512 blocks x 4 rows
    fia_fused<<<grid, block, 0, stream>>>(adj, idx, out);
}

// Round 13
// 27.586 us; speedup vs baseline: 1.4824x; 1.0915x over previous
//
#include <hip/hip_runtime.h>
#include <math.h>

#define N  2048
#define K  8
#define NK 1024
#define R  4             // rows per block
#define TPB 512
#define SLOT NK          // zero slot index in stage rows
#define TAU_C 0.5f
#define TAU_S 0.5f

// Single fused kernel (replay-safe class, R8-R12). Block rebuilds index maps
// from immutable `idx` into LDS, then serves R=4 full output rows.
// R13 changes vs R12: zero-slot staging (select-free sum/cs), scalar-gated
// per-k stats (skip absent clients), exact LUT for C=cs/n (same IEEE bits).
__global__ void __launch_bounds__(TPB, 4)
fia_fused(const float* __restrict__ adj,
          const int*   __restrict__ idx,
          float* __restrict__ out) {
    __shared__ short jj[K][N];          // 32 KB: pos of y in idx[k], or -1
    __shared__ short ixs[K][R];         // pos of row x in idx[k], or -1
    __shared__ float stage[K][NK + 4];  // 32.9 KB: row data + zero slot
    __shared__ float lutCS[81];         // exact IEEE cs/n for all (cnt,cs)

    const int tid = threadIdx.x;
    const int X0  = blockIdx.x * R;

    // ---- one-time init: maps to -1, zero slots, C-LUT (exact IEEE divides)
    {
        int4  m1 = make_int4(-1, -1, -1, -1);
        int4* p4 = (int4*)&jj[0][0];                 // K*N*2/16 = 2048 int4
        #pragma unroll
        for (int q = 0; q < (K * N * 2) / (16 * TPB); ++q)   // 4
            p4[q * TPB + tid] = m1;
        if (tid < K * R) ((short*)ixs)[tid] = (short)-1;
        if (tid < K) stage[tid][SLOT] = 0.0f;        // zero slot per client
        if (tid < 81) {
            int cn = tid / 9, cc = tid % 9;
            lutCS[tid] = (float)cc / fmaxf((float)cn, 1e-5f);  // IEEE divide
        }
    }
    __syncthreads();

    // ---- scan idx (8192 entries, coalesced). Unique writer per cell.
    #pragma unroll
    for (int it = 0; it < (K * NK) / TPB; ++it) {    // 16
        int t   = it * TPB + tid;
        int val = idx[t];                            // coalesced
        int k   = t >> 10;                           // uniform per iteration
        int p   = t & (NK - 1);
        jj[k][val] = (short)p;
        int rel = val - X0;
        if ((unsigned)rel < (unsigned)R) ixs[k][rel] = (short)p;
    }
    __syncthreads();

    // ---- hoisted per-thread column state (reused by all R rows)
    const int y0 = tid * 4;                          // 4 consecutive columns
    int jc[K][4];                                    // gather index or SLOT
    int jmask[4] = {0, 0, 0, 0};
    #pragma unroll
    for (int k = 0; k < K; ++k) {
        short4 v = *(const short4*)&jj[k][y0];       // ds_read_b64
        int j0 = v.x, j1 = v.y, j2 = v.z, j3 = v.w;
        jmask[0] |= (j0 >= 0) ? (1 << k) : 0;
        jmask[1] |= (j1 >= 0) ? (1 << k) : 0;
        jmask[2] |= (j2 >= 0) ? (1 << k) : 0;
        jmask[3] |= (j3 >= 0) ? (1 << k) : 0;
        jc[k][0] = (j0 >= 0) ? j0 : SLOT;            // absent -> zero slot
        jc[k][1] = (j1 >= 0) ? j1 : SLOT;
        jc[k][2] = (j2 >= 0) ? j2 : SLOT;
        jc[k][3] = (j3 >= 0) ? j3 : SLOT;
    }

    // ---- row loop
    #pragma unroll 1
    for (int r = 0; r < R; ++r) {
        int kp = 0;
        int ixr[K];
        #pragma unroll
        for (int k = 0; k < K; ++k) {
            int v = (int)ixs[k][r];                  // uniform LDS read
            ixr[k] = __builtin_amdgcn_readfirstlane(v);
            kp |= (ixr[k] >= 0) ? (1 << k) : 0;
        }

        // STAGE loads first (overlap with prev row's stats in other waves)
        float2 sr[K];
        #pragma unroll
        for (int k = 0; k < K; ++k) {
            if (ixr[k] >= 0) {                       // scalar branch
                const float2* __restrict__ src =
                    (const float2*)(adj + ((size_t)k * NK + (size_t)ixr[k]) * NK);
                sr[k] = src[tid];                    // fully coalesced 8B
            }
        }
        __syncthreads();                             // WAR: prev row done w/ stage
        #pragma unroll
        for (int k = 0; k < K; ++k) {
            if (ixr[k] >= 0)
                ((float2*)&stage[k][0])[tid] = sr[k];   // ds_write_b64
        }
        __syncthreads();                             // stage visible

        // PASS A: gather + sum + cs, scalar-gated per k; select-free
        // (absent lanes read the zero slot -> exact a*mask, reference order).
        float vraw[4][K];                            // only present-k cells used
        float sum[4] = {0.f, 0.f, 0.f, 0.f};
        int   csi[4] = {0, 0, 0, 0};
        #pragma unroll
        for (int k = 0; k < K; ++k) {
            if ((kp >> k) & 1) {                     // SGPR branch
                #pragma unroll
                for (int yy = 0; yy < 4; ++yy) {
                    float a = stage[k][jc[k][yy]];   // ds_read_b32
                    vraw[yy][k] = a;
                    sum[yy] += a;                    // +0.0 for absent == ref
                    csi[yy] += (a > TAU_C) ? 1 : 0;  // absent a=0 -> false
                }
            }
        }

        // PASS B + epilogue: exact reference rounding sequence.
        float res[4];
        #pragma unroll
        for (int yy = 0; yy < 4; ++yy) {
            const int m   = jmask[yy] & kp;
            const int cnt = __popc(m);
            float n    = fmaxf((float)cnt, 1e-5f);
            float mean = sum[yy] / n;                // IEEE divide

            float vs = 0.f;
            #pragma unroll
            for (int k = 0; k < K; ++k) {
                if ((kp >> k) & 1) {                 // SGPR branch
                    bool  p = (m >> k) & 1;
                    float d = vraw[yy][k] - mean;
                    vs += p ? d * d : 0.f;           // select blocks fma-fuse
                }
            }
            float C = lutCS[cnt * 9 + csi[yy]];      // == cs/n, same IEEE bits
            float V = vs / n;                        // IEEE divide
            float S = C * expf(-V);                  // precise expf
            float rr = (S > TAU_S) ? mean : 0.f;
            res[yy] = (cnt > 0) ? rr : 0.f;
        }

        float4 o;
        o.x = res[0]; o.y = res[1]; o.z = res[2]; o.w = res[3];
        *(float4*)(out + (size_t)(X0 + r) * N + y0) = o;
    }
}

extern "C" void kernel_launch(void* const* d_in, const int* in_sizes, int n_in,
                              void* d_out, int out_size, void* d_ws, size_t ws_size,
                              hipStream_t stream) {
    const float* adj = (const float*)d_in[0];        // (K, NK, NK) f32
    const int*   idx = (const int*)d_in[1];          // (K, NK) i32
    float*       out = (float*)d_out;                // (N, N) f32

    dim3 block(TPB, 1, 1);
    dim3 grid(N / R, 1, 1);                          // 512 blocks x 4 rows
    fia_fused<<<grid, block, 0, stream>>>(adj, idx, out);
}